// Round 7
// baseline (318.589 us; speedup 1.0000x reference)
//
#include <hip/hip_runtime.h>

#define D_F 128
#define D_H 512
#define SHS 520   // sH row stride (bf16 elems): 1040 B, 16B-aligned

typedef short v8s __attribute__((ext_vector_type(8)));
typedef float v4f __attribute__((ext_vector_type(4)));
typedef _Float16 v2h __attribute__((ext_vector_type(2)));
typedef int   i8v __attribute__((ext_vector_type(8)));
typedef float f8v __attribute__((ext_vector_type(8)));
typedef unsigned u2v __attribute__((ext_vector_type(2)));

__device__ inline unsigned short f2bf(float f) {
    unsigned u = __float_as_uint(f);
    unsigned r = (u + 0x7fffu + ((u >> 16) & 1u)) >> 16;   // RNE
    return (unsigned short)r;
}
__device__ inline v2h bch(unsigned x) { return __builtin_bit_cast(v2h, x); }

// ---------------------------------------------------------------------------
// prep: weight conversion (all blocks) + init cumsums/zeros/counter (block 0)
// ---------------------------------------------------------------------------
__global__ __launch_bounds__(256) void prep_kernel(
    const float* __restrict__ W1, const float* __restrict__ W2,
    const int* __restrict__ n_node, const int* __restrict__ n_edge,
    unsigned short* __restrict__ W1T, unsigned short* __restrict__ W2T,
    int* __restrict__ ec, int* __restrict__ nid,
    float* __restrict__ ew, float* __restrict__ ga, int* __restrict__ dctr,
    int G, int E)
{
    if (blockIdx.x == 0) {
        __shared__ int sne[512];
        __shared__ int snn[512];
        const int t = threadIdx.x;
        if (t == 0) *dctr = 0;
        for (int g = t; g < G; g += 256) { sne[g] = n_edge[g]; snn[g] = n_node[g]; }
        __syncthreads();
        for (int g = t; g < G; g += 256) {
            int se = 0, sn = 0;
            for (int k = 0; k < g; ++k)  se += sne[k];
            for (int k = 0; k <= g; ++k) sn += snn[k];
            ec[g]  = se;
            nid[g] = sn - 1;
            ew[g] = 0.f;
            ga[g] = 0.f;
            if (g == G - 1) {
                int tot = se + sne[g];
                ec[G] = tot > E ? tot : E;
            }
        }
    }
    int i = blockIdx.x * 256 + threadIdx.x;
    if (i < D_F * D_H) {
        int n = i >> 7, k = i & (D_F - 1);        // W1T[n][k] = W1[k][n]
        W1T[i] = f2bf(W1[k * D_H + n]);
        int n2 = i >> 9, k2 = i & (D_H - 1);      // W2T[n2][k2] = W2[k2][n2]
        W2T[i] = f2bf(W2[k2 * D_F + n2]);
    }
}

// ---------------------------------------------------------------------------
// Fused MLP via MFMA (bf16 weights, fp16 output h): 16 rows / block, 8 waves
// splitting the n-dimension (5000 waves).
// ---------------------------------------------------------------------------
__global__ __launch_bounds__(512) void mlp_mfma_kernel(
    const float* __restrict__ nodes,
    const unsigned short* __restrict__ W1T, const float* __restrict__ b1,
    const unsigned short* __restrict__ W2T, const float* __restrict__ b2,
    _Float16* __restrict__ hh, int N)
{
    __shared__ unsigned short sH[16 * SHS];   // 16.6 KB

    const int t    = threadIdx.x;
    const int wave = t >> 6;        // 0..7
    const int lane = t & 63;
    const int li   = lane & 15;
    const int quad = lane >> 4;
    const int row0 = blockIdx.x * 16;

    // A fragments for GEMM1 (same 16 rows for all 8 waves; L1-served)
    v8s a1[4];
    {
        int r = min(row0 + li, N - 1);
        const float* xp = nodes + (size_t)r * D_F + quad * 8;
        #pragma unroll
        for (int ks = 0; ks < 4; ++ks) {
            float4 f0 = *(const float4*)(xp + ks * 32);
            float4 f1 = *(const float4*)(xp + ks * 32 + 4);
            v8s v;
            v[0] = (short)f2bf(f0.x); v[1] = (short)f2bf(f0.y);
            v[2] = (short)f2bf(f0.z); v[3] = (short)f2bf(f0.w);
            v[4] = (short)f2bf(f1.x); v[5] = (short)f2bf(f1.y);
            v[6] = (short)f2bf(f1.z); v[7] = (short)f2bf(f1.w);
            a1[ks] = v;
        }
    }

    // GEMM1: this wave covers hidden cols [wave*64, wave*64+64)
    #pragma unroll 2
    for (int jj = 0; jj < 4; ++jj) {
        const int n0 = (wave * 4 + jj) * 16;
        const unsigned short* wp = W1T + (size_t)(n0 + li) * D_F + quad * 8;
        v4f acc = {0.f, 0.f, 0.f, 0.f};
        #pragma unroll
        for (int ks = 0; ks < 4; ++ks) {
            v8s b = *(const v8s*)(wp + ks * 32);
            acc = __builtin_amdgcn_mfma_f32_16x16x32_bf16(a1[ks], b, acc, 0, 0, 0);
        }
        float bias = b1[n0 + li];
        #pragma unroll
        for (int r = 0; r < 4; ++r) {
            float hv = fmaxf(acc[r] + bias, 0.f);
            int m = quad * 4 + r;                 // C layout: row = quad*4+reg
            sH[m * SHS + n0 + li] = f2bf(hv);     // col = li
        }
    }
    __syncthreads();

    // A fragments for GEMM2 from LDS
    v8s aH[16];
    #pragma unroll
    for (int ks = 0; ks < 16; ++ks)
        aH[ks] = *(const v8s*)(sH + li * SHS + ks * 32 + quad * 8);

    // GEMM2: this wave covers output cols [wave*16, wave*16+16)
    {
        const int n0 = wave * 16;
        const unsigned short* wp = W2T + (size_t)(n0 + li) * D_H + quad * 8;
        v4f acc = {0.f, 0.f, 0.f, 0.f};
        #pragma unroll
        for (int kc = 0; kc < 2; ++kc) {
            v8s bb[8];
            #pragma unroll
            for (int u = 0; u < 8; ++u)
                bb[u] = *(const v8s*)(wp + (kc * 8 + u) * 32);
            #pragma unroll
            for (int u = 0; u < 8; ++u)
                acc = __builtin_amdgcn_mfma_f32_16x16x32_bf16(aH[kc * 8 + u], bb[u], acc, 0, 0, 0);
        }
        float bias = b2[n0 + li];
        #pragma unroll
        for (int r = 0; r < 4; ++r) {
            int grow = row0 + quad * 4 + r;
            if (grow < N)
                hh[(size_t)grow * D_F + n0 + li] = (_Float16)(acc[r] + bias);
        }
    }
}

// ---------------------------------------------------------------------------
// Edge stage: ONE WAVE PER 64-EDGE TILE (tiles are 64-aligned by grid
// construction). Indices/weights come in via wave-uniform s_load_dwordx8.
// fp16 row = 256 B: lanes 0-31 hold src row (dwordx2 each), lanes 32-63 hold
// dst row -> ONE global_load_dwordx2 per edge covers both rows. Cross-half
// exchange via loop-invariant ds_bpermute(lane^32); packed f16 sub + dot2.
// Both halves compute identical squares -> scale 0.5 at flush; accW summed
// on all 64 lanes -> scale 1/64.
// ---------------------------------------------------------------------------
__global__ __launch_bounds__(256) void edge_kernel(
    const _Float16* __restrict__ hh, const float* __restrict__ wedge,
    const int* __restrict__ senders, const int* __restrict__ receivers,
    const int* __restrict__ ec, const int* __restrict__ nid,
    float* __restrict__ ew, float* __restrict__ ga, int* __restrict__ dctr,
    float* __restrict__ out, int E, int G)
{
    __shared__ int   sLast;
    __shared__ float sred[4];

    const int t       = threadIdx.x;
    const int lane    = t & 63;
    const int xaddr   = (lane ^ 32) << 2;     // bpermute byte-addr, invariant
    const int halfsel = lane & 32;            // 0 = src half, 32 = dst half
    const int loff    = (lane & 31) << 3;     // byte offset within 256 B row
    const unsigned char* __restrict__ hb = (const unsigned char*)hh;

    const int wid = blockIdx.x * 4 + (t >> 6);
    const int tb  = wid << 6;

    if (tb < E) {
        const int tbu   = __builtin_amdgcn_readfirstlane(tb);
        const int ntile = min(64, E - tbu);

        // binary search on global ec (uniform address -> scalar loads)
        int lo = 0, hi = G - 1;
        while (lo < hi) { int m = (lo + hi + 1) >> 1; if (ec[m] <= tbu) lo = m; else hi = m - 1; }
        int gid = lo;
        int segend = ec[gid + 1];

        float accE = 0.f, accW = 0.f;

        if (ntile == 64 && tbu + 64 <= segend) {
            // ---- fast path: full tile, single segment ----
            const i8v* sp8 = (const i8v*)(senders + tbu);   // 32 B-aligned
            const i8v* rp8 = (const i8v*)(receivers + tbu);
            const f8v* wp8 = (const f8v*)(wedge + tbu);
            #pragma unroll 1
            for (int kc = 0; kc < 8; ++kc) {
                i8v s8 = sp8[kc];
                i8v r8 = rp8[kc];
                f8v w8 = wp8[kc];
                u2v d[8];
                #pragma unroll
                for (int u = 0; u < 8; ++u) {
                    int idx = halfsel ? r8[u] : s8[u];
                    d[u] = *(const u2v*)(hb + ((idx << 8) | loff));
                }
                #pragma unroll
                for (int u = 0; u < 8; ++u) {
                    int ox = __builtin_amdgcn_ds_bpermute(xaddr, (int)d[u][0]);
                    int oy = __builtin_amdgcn_ds_bpermute(xaddr, (int)d[u][1]);
                    v2h dx = bch(d[u][0]) - bch((unsigned)ox);
                    v2h dy = bch(d[u][1]) - bch((unsigned)oy);
                    float tt = __builtin_amdgcn_fdot2(dx, dx,
                               __builtin_amdgcn_fdot2(dy, dy, 0.f, false), false);
                    accE = fmaf(w8[u], tt, accE);
                    accW += w8[u];
                }
            }
            float rE = accE, rW = accW;
            #pragma unroll
            for (int m = 32; m > 0; m >>= 1) {
                rE += __shfl_xor(rE, m);
                rW += __shfl_xor(rW, m);
            }
            if (lane == 0) {
                atomicAdd(&ga[gid], rE * 0.5f);
                atomicAdd(&ew[gid], rW * (1.f / 64.f));
            }
        } else {
            // ---- slow path: per-edge with segment flushes ----
            for (int i = 0; i < ntile; ++i) {
                int e = tbu + i;
                while (e >= segend) {
                    float rE = accE, rW = accW;
                    #pragma unroll
                    for (int m = 32; m > 0; m >>= 1) {
                        rE += __shfl_xor(rE, m);
                        rW += __shfl_xor(rW, m);
                    }
                    if (lane == 0 && (rE != 0.f || rW != 0.f)) {
                        atomicAdd(&ga[gid], rE * 0.5f);
                        atomicAdd(&ew[gid], rW * (1.f / 64.f));
                    }
                    accE = 0.f; accW = 0.f;
                    ++gid;
                    segend = ec[gid + 1];
                }
                int s = senders[e];
                int r = receivers[e];
                float w = wedge[e];
                int idx = halfsel ? r : s;
                u2v dv = *(const u2v*)(hb + ((idx << 8) | loff));
                int ox = __builtin_amdgcn_ds_bpermute(xaddr, (int)dv[0]);
                int oy = __builtin_amdgcn_ds_bpermute(xaddr, (int)dv[1]);
                v2h dx = bch(dv[0]) - bch((unsigned)ox);
                v2h dy = bch(dv[1]) - bch((unsigned)oy);
                float tt = __builtin_amdgcn_fdot2(dx, dx,
                           __builtin_amdgcn_fdot2(dy, dy, 0.f, false), false);
                accE = fmaf(w, tt, accE);
                accW += w;
            }
            float rE = accE, rW = accW;
            #pragma unroll
            for (int m = 32; m > 0; m >>= 1) {
                rE += __shfl_xor(rE, m);
                rW += __shfl_xor(rW, m);
            }
            if (lane == 0 && (rE != 0.f || rW != 0.f)) {
                atomicAdd(&ga[gid], rE * 0.5f);
                atomicAdd(&ew[gid], rW * (1.f / 64.f));
            }
        }
    }

    // -------- last block finalizes: node gather + loss ---------------------
    __threadfence();
    if (t == 0) sLast = (atomicAdd(dctr, 1) == gridDim.x - 1) ? 1 : 0;
    __syncthreads();
    if (sLast) {
        __threadfence();
        const int total = G * D_F;
        for (int i = t; i < total; i += 256) {
            int g = i >> 7;
            int c = i & (D_F - 1);
            out[i] = (float)hh[(size_t)nid[g] * D_F + c];
        }
        float p = 0.f;
        for (int g = t; g < G; g += 256) {
            float w = atomicAdd(&ew[g], 0.f);
            float v = atomicAdd(&ga[g], 0.f);
            p += (w != 0.f) ? v / w : 0.f;
        }
        #pragma unroll
        for (int m = 32; m > 0; m >>= 1) p += __shfl_xor(p, m);
        if ((t & 63) == 0) sred[t >> 6] = p;
        __syncthreads();
        if (t == 0)
            out[total] = (sred[0] + sred[1] + sred[2] + sred[3]) / (float)G;
    }
}

// ---------------------------------------------------------------------------
extern "C" void kernel_launch(void* const* d_in, const int* in_sizes, int n_in,
                              void* d_out, int out_size, void* d_ws, size_t ws_size,
                              hipStream_t stream) {
    const float* nodes     = (const float*)d_in[0];
    const float* edges     = (const float*)d_in[1];
    const int*   senders   = (const int*)d_in[2];
    const int*   receivers = (const int*)d_in[3];
    const int*   n_node    = (const int*)d_in[4];
    const int*   n_edge    = (const int*)d_in[5];
    const float* W1        = (const float*)d_in[6];
    const float* b1        = (const float*)d_in[7];
    const float* W2        = (const float*)d_in[8];
    const float* b2        = (const float*)d_in[9];

    const int N = in_sizes[0] / D_F;
    const int E = in_sizes[1];
    const int G = in_sizes[4];

    float* out = (float*)d_out;

    // workspace: hh f16 | W1T bf16 | W2T bf16 | ec | nid | ew | ga | dctr
    _Float16*       hh  = (_Float16*)d_ws;
    unsigned short* W1T = (unsigned short*)(hh + (size_t)N * D_F);
    unsigned short* W2T = W1T + (size_t)D_F * D_H;
    int*            ec  = (int*)(W2T + (size_t)D_F * D_H);
    int*            nid = ec + (G + 1);
    float*          ew  = (float*)(nid + G);
    float*          ga  = ew + G;
    int*            dctr = (int*)(ga + G);

    prep_kernel<<<(D_F * D_H + 255) / 256, 256, 0, stream>>>(
        W1, W2, n_node, n_edge, W1T, W2T, ec, nid, ew, ga, dctr, G, E);

    const int nblk = (N + 15) / 16;
    mlp_mfma_kernel<<<nblk, 512, 0, stream>>>(nodes, W1T, b1, W2T, b2, hh, N);

    const int ntiles = (E + 63) / 64;
    const int eblk   = (ntiles + 3) / 4;
    edge_kernel<<<eblk, 256, 0, stream>>>(hh, edges, senders, receivers, ec, nid,
                                          ew, ga, dctr, out, E, G);
}

// Round 8
// 290.760 us; speedup vs baseline: 1.0957x; 1.0957x over previous
//
#include <hip/hip_runtime.h>

#define D_F 128
#define D_H 512
#define SHS 520   // sH row stride (bf16 elems): 1040 B, 16B-aligned

typedef short v8s __attribute__((ext_vector_type(8)));
typedef float v4f __attribute__((ext_vector_type(4)));
typedef _Float16 v2h __attribute__((ext_vector_type(2)));

__device__ inline unsigned short f2bf(float f) {
    unsigned u = __float_as_uint(f);
    unsigned r = (u + 0x7fffu + ((u >> 16) & 1u)) >> 16;   // RNE
    return (unsigned short)r;
}
__device__ inline v2h bch(unsigned x) { return __builtin_bit_cast(v2h, x); }

// ---------------------------------------------------------------------------
// prep: weight conversion (all blocks) + init cumsums/zeros/counter (block 0)
// ---------------------------------------------------------------------------
__global__ __launch_bounds__(256) void prep_kernel(
    const float* __restrict__ W1, const float* __restrict__ W2,
    const int* __restrict__ n_node, const int* __restrict__ n_edge,
    unsigned short* __restrict__ W1T, unsigned short* __restrict__ W2T,
    int* __restrict__ ec, int* __restrict__ nid,
    float* __restrict__ ew, float* __restrict__ ga, int* __restrict__ dctr,
    int G, int E)
{
    if (blockIdx.x == 0) {
        __shared__ int sne[512];
        __shared__ int snn[512];
        const int t = threadIdx.x;
        if (t == 0) *dctr = 0;
        for (int g = t; g < G; g += 256) { sne[g] = n_edge[g]; snn[g] = n_node[g]; }
        __syncthreads();
        for (int g = t; g < G; g += 256) {
            int se = 0, sn = 0;
            for (int k = 0; k < g; ++k)  se += sne[k];
            for (int k = 0; k <= g; ++k) sn += snn[k];
            ec[g]  = se;
            nid[g] = sn - 1;
            ew[g] = 0.f;
            ga[g] = 0.f;
            if (g == G - 1) {
                int tot = se + sne[g];
                ec[G] = tot > E ? tot : E;
            }
        }
    }
    int i = blockIdx.x * 256 + threadIdx.x;
    if (i < D_F * D_H) {
        int n = i >> 7, k = i & (D_F - 1);        // W1T[n][k] = W1[k][n]
        W1T[i] = f2bf(W1[k * D_H + n]);
        int n2 = i >> 9, k2 = i & (D_H - 1);      // W2T[n2][k2] = W2[k2][n2]
        W2T[i] = f2bf(W2[k2 * D_F + n2]);
    }
}

// ---------------------------------------------------------------------------
// Fused MLP via MFMA (bf16 weights, fp16 output h): 16 rows / block, 8 waves
// splitting the n-dimension (5000 waves).
// ---------------------------------------------------------------------------
__global__ __launch_bounds__(512) void mlp_mfma_kernel(
    const float* __restrict__ nodes,
    const unsigned short* __restrict__ W1T, const float* __restrict__ b1,
    const unsigned short* __restrict__ W2T, const float* __restrict__ b2,
    _Float16* __restrict__ hh, int N)
{
    __shared__ unsigned short sH[16 * SHS];   // 16.6 KB

    const int t    = threadIdx.x;
    const int wave = t >> 6;        // 0..7
    const int lane = t & 63;
    const int li   = lane & 15;
    const int quad = lane >> 4;
    const int row0 = blockIdx.x * 16;

    // A fragments for GEMM1 (same 16 rows for all 8 waves; L1-served)
    v8s a1[4];
    {
        int r = min(row0 + li, N - 1);
        const float* xp = nodes + (size_t)r * D_F + quad * 8;
        #pragma unroll
        for (int ks = 0; ks < 4; ++ks) {
            float4 f0 = *(const float4*)(xp + ks * 32);
            float4 f1 = *(const float4*)(xp + ks * 32 + 4);
            v8s v;
            v[0] = (short)f2bf(f0.x); v[1] = (short)f2bf(f0.y);
            v[2] = (short)f2bf(f0.z); v[3] = (short)f2bf(f0.w);
            v[4] = (short)f2bf(f1.x); v[5] = (short)f2bf(f1.y);
            v[6] = (short)f2bf(f1.z); v[7] = (short)f2bf(f1.w);
            a1[ks] = v;
        }
    }

    // GEMM1: this wave covers hidden cols [wave*64, wave*64+64)
    #pragma unroll 2
    for (int jj = 0; jj < 4; ++jj) {
        const int n0 = (wave * 4 + jj) * 16;
        const unsigned short* wp = W1T + (size_t)(n0 + li) * D_F + quad * 8;
        v4f acc = {0.f, 0.f, 0.f, 0.f};
        #pragma unroll
        for (int ks = 0; ks < 4; ++ks) {
            v8s b = *(const v8s*)(wp + ks * 32);
            acc = __builtin_amdgcn_mfma_f32_16x16x32_bf16(a1[ks], b, acc, 0, 0, 0);
        }
        float bias = b1[n0 + li];
        #pragma unroll
        for (int r = 0; r < 4; ++r) {
            float hv = fmaxf(acc[r] + bias, 0.f);
            int m = quad * 4 + r;                 // C layout: row = quad*4+reg
            sH[m * SHS + n0 + li] = f2bf(hv);     // col = li
        }
    }
    __syncthreads();

    // A fragments for GEMM2 from LDS
    v8s aH[16];
    #pragma unroll
    for (int ks = 0; ks < 16; ++ks)
        aH[ks] = *(const v8s*)(sH + li * SHS + ks * 32 + quad * 8);

    // GEMM2: this wave covers output cols [wave*16, wave*16+16)
    {
        const int n0 = wave * 16;
        const unsigned short* wp = W2T + (size_t)(n0 + li) * D_H + quad * 8;
        v4f acc = {0.f, 0.f, 0.f, 0.f};
        #pragma unroll
        for (int kc = 0; kc < 2; ++kc) {
            v8s bb[8];
            #pragma unroll
            for (int u = 0; u < 8; ++u)
                bb[u] = *(const v8s*)(wp + (kc * 8 + u) * 32);
            #pragma unroll
            for (int u = 0; u < 8; ++u)
                acc = __builtin_amdgcn_mfma_f32_16x16x32_bf16(aH[kc * 8 + u], bb[u], acc, 0, 0, 0);
        }
        float bias = b2[n0 + li];
        #pragma unroll
        for (int r = 0; r < 4; ++r) {
            int grow = row0 + quad * 4 + r;
            if (grow < N)
                hh[(size_t)grow * D_F + n0 + li] = (_Float16)(acc[r] + bias);
        }
    }
}

// ---------------------------------------------------------------------------
// Edge stage (r4 structure, fp16 math): one wave per edge stream, lane l owns
// dims {2l,2l+1} (one dword); each gather instruction covers ONE row, fully
// coalesced 256 B. __shfl broadcast of indices/weights, 8-edge batches for
// MLP. Per-lane accumulation; 64-lane reduce only at segment flush.
// LDS-staged atomics; last block finalizes output.
// ---------------------------------------------------------------------------
__global__ __launch_bounds__(256) void edge_kernel(
    const _Float16* __restrict__ hh, const float* __restrict__ wedge,
    const int* __restrict__ senders, const int* __restrict__ receivers,
    const int* __restrict__ ec, const int* __restrict__ nid,
    float* __restrict__ ew, float* __restrict__ ga, int* __restrict__ dctr,
    float* __restrict__ out, int E, int G)
{
    __shared__ int   sec[513];
    __shared__ float sga[512];
    __shared__ float sew[512];
    __shared__ int   sLast;
    __shared__ float sred[4];
    const int t = threadIdx.x;
    for (int i = t; i <= G; i += 256) sec[i] = ec[i];
    for (int i = t; i < G;  i += 256) { sga[i] = 0.f; sew[i] = 0.f; }
    __syncthreads();

    const unsigned* __restrict__ h32 = (const unsigned*)hh;   // row = 64 dwords
    const int lane   = t & 63;
    const int wid    = blockIdx.x * 4 + (t >> 6);
    const int nwaves = gridDim.x * 4;
    const int chunk  = (E + nwaves - 1) / nwaves;
    const int e0 = wid * chunk;
    const int e1 = min(E, e0 + chunk);

    if (e0 < e1) {
        int gid;
        { int lo = 0, hi = G - 1;
          while (lo < hi) { int m = (lo + hi + 1) >> 1; if (sec[m] <= e0) lo = m; else hi = m - 1; }
          gid = lo; }

        float accE = 0.f, accW = 0.f;

        for (int tb = e0; tb < e1; tb += 64) {
            const int nt  = min(64, e1 - tb);
            const int ecl = min(tb + lane, e1 - 1);
            const bool vld = (tb + lane) < e1;
            int   sv = __builtin_nontemporal_load(senders + ecl);
            int   rv = __builtin_nontemporal_load(receivers + ecl);
            float wv = vld ? __builtin_nontemporal_load(wedge + ecl) : 0.f;

            if (tb + nt <= sec[gid + 1]) {
                // fast path: whole tile in current segment (w=0 tails ok)
                #pragma unroll 1
                for (int i = 0; i < 64; i += 8) {
                    unsigned a[8], b[8];
                    int su[8], ru[8];
                    #pragma unroll
                    for (int u = 0; u < 8; ++u) {
                        su[u] = __shfl(sv, i + u);
                        ru[u] = __shfl(rv, i + u);
                    }
                    #pragma unroll
                    for (int u = 0; u < 8; ++u) {
                        a[u] = h32[(unsigned)((su[u] << 6) | lane)];
                        b[u] = h32[(unsigned)((ru[u] << 6) | lane)];
                    }
                    #pragma unroll
                    for (int u = 0; u < 8; ++u) {
                        float w = __shfl(wv, i + u);
                        v2h d  = bch(a[u]) - bch(b[u]);
                        float tt = __builtin_amdgcn_fdot2(d, d, 0.f, false);
                        accE = fmaf(w, tt, accE);
                    }
                }
                accW += wv;   // own-lane weight; lane-sum = tile sum
            } else {
                // boundary tile: per-edge with segment flushes
                for (int i = 0; i < nt; ++i) {
                    int e = tb + i;
                    while (e >= sec[gid + 1]) {
                        float rE = accE, rW = accW;
                        #pragma unroll
                        for (int m = 32; m > 0; m >>= 1) {
                            rE += __shfl_xor(rE, m);
                            rW += __shfl_xor(rW, m);
                        }
                        if (lane == 0 && (rE != 0.f || rW != 0.f)) {
                            atomicAdd(&sga[gid], rE);
                            atomicAdd(&sew[gid], rW);
                        }
                        accE = 0.f; accW = 0.f;
                        ++gid;
                    }
                    int   s = __shfl(sv, i);
                    int   r = __shfl(rv, i);
                    float w = __shfl(wv, i);
                    unsigned a = h32[(unsigned)((s << 6) | lane)];
                    unsigned b = h32[(unsigned)((r << 6) | lane)];
                    v2h d = bch(a) - bch(b);
                    float tt = __builtin_amdgcn_fdot2(d, d, 0.f, false);
                    accE = fmaf(w, tt, accE);
                    if (lane == 0) accW += w;
                }
            }
        }
        // final flush
        float rE = accE, rW = accW;
        #pragma unroll
        for (int m = 32; m > 0; m >>= 1) {
            rE += __shfl_xor(rE, m);
            rW += __shfl_xor(rW, m);
        }
        if (lane == 0 && (rE != 0.f || rW != 0.f)) {
            atomicAdd(&sga[gid], rE);
            atomicAdd(&sew[gid], rW);
        }
    }

    __syncthreads();
    for (int g = t; g < G; g += 256) {
        float vg = sga[g], vw = sew[g];
        if (vg != 0.f || vw != 0.f) {
            atomicAdd(&ga[g], vg);
            atomicAdd(&ew[g], vw);
        }
    }

    // -------- last block finalizes: node gather + loss ---------------------
    __threadfence();
    if (t == 0) sLast = (atomicAdd(dctr, 1) == gridDim.x - 1) ? 1 : 0;
    __syncthreads();
    if (sLast) {
        __threadfence();
        const int total = G * D_F;
        for (int i = t; i < total; i += 256) {
            int g = i >> 7;
            int c = i & (D_F - 1);
            out[i] = (float)hh[(size_t)nid[g] * D_F + c];
        }
        float p = 0.f;
        for (int g = t; g < G; g += 256) {
            float w = atomicAdd(&ew[g], 0.f);
            float v = atomicAdd(&ga[g], 0.f);
            p += (w != 0.f) ? v / w : 0.f;
        }
        #pragma unroll
        for (int m = 32; m > 0; m >>= 1) p += __shfl_xor(p, m);
        if ((t & 63) == 0) sred[t >> 6] = p;
        __syncthreads();
        if (t == 0)
            out[total] = (sred[0] + sred[1] + sred[2] + sred[3]) / (float)G;
    }
}

// ---------------------------------------------------------------------------
extern "C" void kernel_launch(void* const* d_in, const int* in_sizes, int n_in,
                              void* d_out, int out_size, void* d_ws, size_t ws_size,
                              hipStream_t stream) {
    const float* nodes     = (const float*)d_in[0];
    const float* edges     = (const float*)d_in[1];
    const int*   senders   = (const int*)d_in[2];
    const int*   receivers = (const int*)d_in[3];
    const int*   n_node    = (const int*)d_in[4];
    const int*   n_edge    = (const int*)d_in[5];
    const float* W1        = (const float*)d_in[6];
    const float* b1        = (const float*)d_in[7];
    const float* W2        = (const float*)d_in[8];
    const float* b2        = (const float*)d_in[9];

    const int N = in_sizes[0] / D_F;
    const int E = in_sizes[1];
    const int G = in_sizes[4];

    float* out = (float*)d_out;

    // workspace: hh f16 | W1T bf16 | W2T bf16 | ec | nid | ew | ga | dctr
    _Float16*       hh  = (_Float16*)d_ws;
    unsigned short* W1T = (unsigned short*)(hh + (size_t)N * D_F);
    unsigned short* W2T = W1T + (size_t)D_F * D_H;
    int*            ec  = (int*)(W2T + (size_t)D_F * D_H);
    int*            nid = ec + (G + 1);
    float*          ew  = (float*)(nid + G);
    float*          ga  = ew + G;
    int*            dctr = (int*)(ga + G);

    prep_kernel<<<(D_F * D_H + 255) / 256, 256, 0, stream>>>(
        W1, W2, n_node, n_edge, W1T, W2T, ec, nid, ew, ga, dctr, G, E);

    const int nblk = (N + 15) / 16;
    mlp_mfma_kernel<<<nblk, 512, 0, stream>>>(nodes, W1T, b1, W2T, b2, hh, N);

    edge_kernel<<<2048, 256, 0, stream>>>(hh, edges, senders, receivers, ec, nid,
                                          ew, ga, dctr, out, E, G);
}

// Round 9
// 159.227 us; speedup vs baseline: 2.0009x; 1.8261x over previous
//
#include <hip/hip_runtime.h>

#define D_F 128
#define D_H 512
#define SHS 520   // sH row stride (bf16 elems): 1040 B, 16B-aligned

typedef short v8s __attribute__((ext_vector_type(8)));
typedef float v4f __attribute__((ext_vector_type(4)));
typedef _Float16 v2h __attribute__((ext_vector_type(2)));

__device__ inline unsigned short f2bf(float f) {
    unsigned u = __float_as_uint(f);
    unsigned r = (u + 0x7fffu + ((u >> 16) & 1u)) >> 16;   // RNE
    return (unsigned short)r;
}
__device__ inline v2h bch(unsigned x) { return __builtin_bit_cast(v2h, x); }

// ---------------------------------------------------------------------------
// prep: weight conversion (all blocks) + init cumsums/zeros (block 0)
// ---------------------------------------------------------------------------
__global__ __launch_bounds__(256) void prep_kernel(
    const float* __restrict__ W1, const float* __restrict__ W2,
    const int* __restrict__ n_node, const int* __restrict__ n_edge,
    unsigned short* __restrict__ W1T, unsigned short* __restrict__ W2T,
    int* __restrict__ ec, int* __restrict__ nid,
    float* __restrict__ ew, float* __restrict__ ga, int G, int E)
{
    if (blockIdx.x == 0) {
        __shared__ int sne[512];
        __shared__ int snn[512];
        const int t = threadIdx.x;
        for (int g = t; g < G; g += 256) { sne[g] = n_edge[g]; snn[g] = n_node[g]; }
        __syncthreads();
        for (int g = t; g < G; g += 256) {
            int se = 0, sn = 0;
            for (int k = 0; k < g; ++k)  se += sne[k];
            for (int k = 0; k <= g; ++k) sn += snn[k];
            ec[g]  = se;
            nid[g] = sn - 1;
            ew[g] = 0.f;
            ga[g] = 0.f;
            if (g == G - 1) {
                int tot = se + sne[g];
                ec[G] = tot > E ? tot : E;
            }
        }
    }
    int i = blockIdx.x * 256 + threadIdx.x;
    if (i < D_F * D_H) {
        int n = i >> 7, k = i & (D_F - 1);        // W1T[n][k] = W1[k][n]
        W1T[i] = f2bf(W1[k * D_H + n]);
        int n2 = i >> 9, k2 = i & (D_H - 1);      // W2T[n2][k2] = W2[k2][n2]
        W2T[i] = f2bf(W2[k2 * D_F + n2]);
    }
}

// ---------------------------------------------------------------------------
// Fused MLP via MFMA (bf16 weights, fp16 output h): 16 rows / block, 8 waves
// splitting the n-dimension (5000 waves).
// ---------------------------------------------------------------------------
__global__ __launch_bounds__(512) void mlp_mfma_kernel(
    const float* __restrict__ nodes,
    const unsigned short* __restrict__ W1T, const float* __restrict__ b1,
    const unsigned short* __restrict__ W2T, const float* __restrict__ b2,
    _Float16* __restrict__ hh, int N)
{
    __shared__ unsigned short sH[16 * SHS];   // 16.6 KB

    const int t    = threadIdx.x;
    const int wave = t >> 6;        // 0..7
    const int lane = t & 63;
    const int li   = lane & 15;
    const int quad = lane >> 4;
    const int row0 = blockIdx.x * 16;

    // A fragments for GEMM1 (same 16 rows for all 8 waves; L1-served)
    v8s a1[4];
    {
        int r = min(row0 + li, N - 1);
        const float* xp = nodes + (size_t)r * D_F + quad * 8;
        #pragma unroll
        for (int ks = 0; ks < 4; ++ks) {
            float4 f0 = *(const float4*)(xp + ks * 32);
            float4 f1 = *(const float4*)(xp + ks * 32 + 4);
            v8s v;
            v[0] = (short)f2bf(f0.x); v[1] = (short)f2bf(f0.y);
            v[2] = (short)f2bf(f0.z); v[3] = (short)f2bf(f0.w);
            v[4] = (short)f2bf(f1.x); v[5] = (short)f2bf(f1.y);
            v[6] = (short)f2bf(f1.z); v[7] = (short)f2bf(f1.w);
            a1[ks] = v;
        }
    }

    // GEMM1: this wave covers hidden cols [wave*64, wave*64+64)
    #pragma unroll 2
    for (int jj = 0; jj < 4; ++jj) {
        const int n0 = (wave * 4 + jj) * 16;
        const unsigned short* wp = W1T + (size_t)(n0 + li) * D_F + quad * 8;
        v4f acc = {0.f, 0.f, 0.f, 0.f};
        #pragma unroll
        for (int ks = 0; ks < 4; ++ks) {
            v8s b = *(const v8s*)(wp + ks * 32);
            acc = __builtin_amdgcn_mfma_f32_16x16x32_bf16(a1[ks], b, acc, 0, 0, 0);
        }
        float bias = b1[n0 + li];
        #pragma unroll
        for (int r = 0; r < 4; ++r) {
            float hv = fmaxf(acc[r] + bias, 0.f);
            int m = quad * 4 + r;                 // C layout: row = quad*4+reg
            sH[m * SHS + n0 + li] = f2bf(hv);     // col = li
        }
    }
    __syncthreads();

    // A fragments for GEMM2 from LDS
    v8s aH[16];
    #pragma unroll
    for (int ks = 0; ks < 16; ++ks)
        aH[ks] = *(const v8s*)(sH + li * SHS + ks * 32 + quad * 8);

    // GEMM2: this wave covers output cols [wave*16, wave*16+16)
    {
        const int n0 = wave * 16;
        const unsigned short* wp = W2T + (size_t)(n0 + li) * D_H + quad * 8;
        v4f acc = {0.f, 0.f, 0.f, 0.f};
        #pragma unroll
        for (int kc = 0; kc < 2; ++kc) {
            v8s bb[8];
            #pragma unroll
            for (int u = 0; u < 8; ++u)
                bb[u] = *(const v8s*)(wp + (kc * 8 + u) * 32);
            #pragma unroll
            for (int u = 0; u < 8; ++u)
                acc = __builtin_amdgcn_mfma_f32_16x16x32_bf16(aH[kc * 8 + u], bb[u], acc, 0, 0, 0);
        }
        float bias = b2[n0 + li];
        #pragma unroll
        for (int r = 0; r < 4; ++r) {
            int grow = row0 + quad * 4 + r;
            if (grow < N)
                hh[(size_t)grow * D_F + n0 + li] = (_Float16)(acc[r] + bias);
        }
    }
}

// ---------------------------------------------------------------------------
// Edge stage (r4 structure, fp16 math, NO device fence): one wave per edge
// stream; lane l owns dims {2l,2l+1}; each gather covers ONE row (fully
// coalesced 256 B). __shfl broadcast, 8-edge batches. Per-lane accumulation;
// 64-lane reduce only at segment flush. LDS-staged atomics.
// ---------------------------------------------------------------------------
__global__ __launch_bounds__(256) void edge_kernel(
    const _Float16* __restrict__ hh, const float* __restrict__ wedge,
    const int* __restrict__ senders, const int* __restrict__ receivers,
    const int* __restrict__ ec,
    float* __restrict__ ew, float* __restrict__ ga,
    int E, int G)
{
    __shared__ int   sec[513];
    __shared__ float sga[512];
    __shared__ float sew[512];
    const int t = threadIdx.x;
    for (int i = t; i <= G; i += 256) sec[i] = ec[i];
    for (int i = t; i < G;  i += 256) { sga[i] = 0.f; sew[i] = 0.f; }
    __syncthreads();

    const unsigned* __restrict__ h32 = (const unsigned*)hh;   // row = 64 dwords
    const int lane   = t & 63;
    const int wid    = blockIdx.x * 4 + (t >> 6);
    const int nwaves = gridDim.x * 4;
    const int chunk  = (E + nwaves - 1) / nwaves;
    const int e0 = wid * chunk;
    const int e1 = min(E, e0 + chunk);

    if (e0 < e1) {
        int gid;
        { int lo = 0, hi = G - 1;
          while (lo < hi) { int m = (lo + hi + 1) >> 1; if (sec[m] <= e0) lo = m; else hi = m - 1; }
          gid = lo; }

        float accE = 0.f, accW = 0.f;

        for (int tb = e0; tb < e1; tb += 64) {
            const int nt  = min(64, e1 - tb);
            const int ecl = min(tb + lane, e1 - 1);
            const bool vld = (tb + lane) < e1;
            int   sv = __builtin_nontemporal_load(senders + ecl);
            int   rv = __builtin_nontemporal_load(receivers + ecl);
            float wv = vld ? __builtin_nontemporal_load(wedge + ecl) : 0.f;

            if (tb + nt <= sec[gid + 1]) {
                // fast path: whole tile in current segment (w=0 tails ok)
                #pragma unroll 1
                for (int i = 0; i < 64; i += 8) {
                    unsigned a[8], b[8];
                    int su[8], ru[8];
                    #pragma unroll
                    for (int u = 0; u < 8; ++u) {
                        su[u] = __shfl(sv, i + u);
                        ru[u] = __shfl(rv, i + u);
                    }
                    #pragma unroll
                    for (int u = 0; u < 8; ++u) {
                        a[u] = h32[(unsigned)((su[u] << 6) | lane)];
                        b[u] = h32[(unsigned)((ru[u] << 6) | lane)];
                    }
                    #pragma unroll
                    for (int u = 0; u < 8; ++u) {
                        float w = __shfl(wv, i + u);
                        v2h d  = bch(a[u]) - bch(b[u]);
                        float tt = __builtin_amdgcn_fdot2(d, d, 0.f, false);
                        accE = fmaf(w, tt, accE);
                    }
                }
                accW += wv;   // own-lane weight; lane-sum = tile sum
            } else {
                // boundary tile: per-edge with segment flushes
                for (int i = 0; i < nt; ++i) {
                    int e = tb + i;
                    while (e >= sec[gid + 1]) {
                        float rE = accE, rW = accW;
                        #pragma unroll
                        for (int m = 32; m > 0; m >>= 1) {
                            rE += __shfl_xor(rE, m);
                            rW += __shfl_xor(rW, m);
                        }
                        if (lane == 0 && (rE != 0.f || rW != 0.f)) {
                            atomicAdd(&sga[gid], rE);
                            atomicAdd(&sew[gid], rW);
                        }
                        accE = 0.f; accW = 0.f;
                        ++gid;
                    }
                    int   s = __shfl(sv, i);
                    int   r = __shfl(rv, i);
                    float w = __shfl(wv, i);
                    unsigned a = h32[(unsigned)((s << 6) | lane)];
                    unsigned b = h32[(unsigned)((r << 6) | lane)];
                    v2h d = bch(a) - bch(b);
                    float tt = __builtin_amdgcn_fdot2(d, d, 0.f, false);
                    accE = fmaf(w, tt, accE);
                    if (lane == 0) accW += w;
                }
            }
        }
        // final flush
        float rE = accE, rW = accW;
        #pragma unroll
        for (int m = 32; m > 0; m >>= 1) {
            rE += __shfl_xor(rE, m);
            rW += __shfl_xor(rW, m);
        }
        if (lane == 0 && (rE != 0.f || rW != 0.f)) {
            atomicAdd(&sga[gid], rE);
            atomicAdd(&sew[gid], rW);
        }
    }

    __syncthreads();
    for (int g = t; g < G; g += 256) {
        float vg = sga[g], vw = sew[g];
        if (vg != 0.f || vw != 0.f) {
            atomicAdd(&ga[g], vg);
            atomicAdd(&ew[g], vw);
        }
    }
}

// ---------------------------------------------------------------------------
// Finalize: block g < G gathers node_out row; block G computes loss.
// ---------------------------------------------------------------------------
__global__ __launch_bounds__(128) void finalize_kernel(
    const _Float16* __restrict__ hh, const int* __restrict__ nid,
    const float* __restrict__ ew, const float* __restrict__ ga,
    float* __restrict__ out, int G)
{
    const int g = blockIdx.x;
    const int t = threadIdx.x;
    if (g < G) {
        int src = nid[g];
        out[(size_t)g * D_F + t] = (float)hh[(size_t)src * D_F + t];
    } else {
        float p = 0.f;
        for (int i = t; i < G; i += 128) {
            float w = ew[i];
            p += (w != 0.f) ? ga[i] / w : 0.f;
        }
        #pragma unroll
        for (int m = 32; m > 0; m >>= 1) p += __shfl_xor(p, m);
        __shared__ float sp[2];
        if ((t & 63) == 0) sp[t >> 6] = p;
        __syncthreads();
        if (t == 0) out[(size_t)G * D_F] = (sp[0] + sp[1]) / (float)G;
    }
}

// ---------------------------------------------------------------------------
extern "C" void kernel_launch(void* const* d_in, const int* in_sizes, int n_in,
                              void* d_out, int out_size, void* d_ws, size_t ws_size,
                              hipStream_t stream) {
    const float* nodes     = (const float*)d_in[0];
    const float* edges     = (const float*)d_in[1];
    const int*   senders   = (const int*)d_in[2];
    const int*   receivers = (const int*)d_in[3];
    const int*   n_node    = (const int*)d_in[4];
    const int*   n_edge    = (const int*)d_in[5];
    const float* W1        = (const float*)d_in[6];
    const float* b1        = (const float*)d_in[7];
    const float* W2        = (const float*)d_in[8];
    const float* b2        = (const float*)d_in[9];

    const int N = in_sizes[0] / D_F;
    const int E = in_sizes[1];
    const int G = in_sizes[4];

    float* out = (float*)d_out;

    // workspace: hh f16 | W1T bf16 | W2T bf16 | ec | nid | ew | ga
    _Float16*       hh  = (_Float16*)d_ws;
    unsigned short* W1T = (unsigned short*)(hh + (size_t)N * D_F);
    unsigned short* W2T = W1T + (size_t)D_F * D_H;
    int*            ec  = (int*)(W2T + (size_t)D_F * D_H);
    int*            nid = ec + (G + 1);
    float*          ew  = (float*)(nid + G);
    float*          ga  = ew + G;

    prep_kernel<<<(D_F * D_H + 255) / 256, 256, 0, stream>>>(
        W1, W2, n_node, n_edge, W1T, W2T, ec, nid, ew, ga, G, E);

    const int nblk = (N + 15) / 16;
    mlp_mfma_kernel<<<nblk, 512, 0, stream>>>(nodes, W1T, b1, W2T, b2, hh, N);

    edge_kernel<<<2048, 256, 0, stream>>>(hh, edges, senders, receivers, ec,
                                          ew, ga, E, G);

    finalize_kernel<<<G + 1, 128, 0, stream>>>(hh, nid, ew, ga, out, G);
}

// Round 10
// 139.994 us; speedup vs baseline: 2.2757x; 1.1374x over previous
//
#include <hip/hip_runtime.h>

#define D_F 128
#define D_H 512
#define SHS 520   // sH row stride (bf16 elems): 1040 B, 16B-aligned

typedef short v8s __attribute__((ext_vector_type(8)));
typedef float v4f __attribute__((ext_vector_type(4)));
typedef _Float16 v2h __attribute__((ext_vector_type(2)));

__device__ inline unsigned short f2bf(float f) {
    unsigned u = __float_as_uint(f);
    unsigned r = (u + 0x7fffu + ((u >> 16) & 1u)) >> 16;   // RNE
    return (unsigned short)r;
}
__device__ inline v2h bch(unsigned x) { return __builtin_bit_cast(v2h, x); }

// ---------------------------------------------------------------------------
// prep: weight conversion (all blocks) + init cumsums/zeros (block 0)
// ---------------------------------------------------------------------------
__global__ __launch_bounds__(256) void prep_kernel(
    const float* __restrict__ W1, const float* __restrict__ W2,
    const int* __restrict__ n_node, const int* __restrict__ n_edge,
    unsigned short* __restrict__ W1T, unsigned short* __restrict__ W2T,
    int* __restrict__ ec, int* __restrict__ nid,
    float* __restrict__ ew, float* __restrict__ ga, int G, int E)
{
    if (blockIdx.x == 0) {
        __shared__ int sne[512];
        __shared__ int snn[512];
        const int t = threadIdx.x;
        for (int g = t; g < G; g += 256) { sne[g] = n_edge[g]; snn[g] = n_node[g]; }
        __syncthreads();
        for (int g = t; g < G; g += 256) {
            int se = 0, sn = 0;
            for (int k = 0; k < g; ++k)  se += sne[k];
            for (int k = 0; k <= g; ++k) sn += snn[k];
            ec[g]  = se;
            nid[g] = sn - 1;
            ew[g] = 0.f;
            ga[g] = 0.f;
            if (g == G - 1) {
                int tot = se + sne[g];
                ec[G] = tot > E ? tot : E;
            }
        }
    }
    int i = blockIdx.x * 256 + threadIdx.x;
    if (i < D_F * D_H) {
        int n = i >> 7, k = i & (D_F - 1);        // W1T[n][k] = W1[k][n]
        W1T[i] = f2bf(W1[k * D_H + n]);
        int n2 = i >> 9, k2 = i & (D_H - 1);      // W2T[n2][k2] = W2[k2][n2]
        W2T[i] = f2bf(W2[k2 * D_F + n2]);
    }
}

// ---------------------------------------------------------------------------
// Fused MLP via MFMA (bf16 weights, fp16 output h): 16 rows / block, 8 waves
// splitting the n-dimension (5000 waves).
// ---------------------------------------------------------------------------
__global__ __launch_bounds__(512) void mlp_mfma_kernel(
    const float* __restrict__ nodes,
    const unsigned short* __restrict__ W1T, const float* __restrict__ b1,
    const unsigned short* __restrict__ W2T, const float* __restrict__ b2,
    _Float16* __restrict__ hh, int N)
{
    __shared__ unsigned short sH[16 * SHS];   // 16.6 KB

    const int t    = threadIdx.x;
    const int wave = t >> 6;        // 0..7
    const int lane = t & 63;
    const int li   = lane & 15;
    const int quad = lane >> 4;
    const int row0 = blockIdx.x * 16;

    // A fragments for GEMM1 (same 16 rows for all 8 waves; L1-served)
    v8s a1[4];
    {
        int r = min(row0 + li, N - 1);
        const float* xp = nodes + (size_t)r * D_F + quad * 8;
        #pragma unroll
        for (int ks = 0; ks < 4; ++ks) {
            float4 f0 = *(const float4*)(xp + ks * 32);
            float4 f1 = *(const float4*)(xp + ks * 32 + 4);
            v8s v;
            v[0] = (short)f2bf(f0.x); v[1] = (short)f2bf(f0.y);
            v[2] = (short)f2bf(f0.z); v[3] = (short)f2bf(f0.w);
            v[4] = (short)f2bf(f1.x); v[5] = (short)f2bf(f1.y);
            v[6] = (short)f2bf(f1.z); v[7] = (short)f2bf(f1.w);
            a1[ks] = v;
        }
    }

    // GEMM1: this wave covers hidden cols [wave*64, wave*64+64)
    #pragma unroll 2
    for (int jj = 0; jj < 4; ++jj) {
        const int n0 = (wave * 4 + jj) * 16;
        const unsigned short* wp = W1T + (size_t)(n0 + li) * D_F + quad * 8;
        v4f acc = {0.f, 0.f, 0.f, 0.f};
        #pragma unroll
        for (int ks = 0; ks < 4; ++ks) {
            v8s b = *(const v8s*)(wp + ks * 32);
            acc = __builtin_amdgcn_mfma_f32_16x16x32_bf16(a1[ks], b, acc, 0, 0, 0);
        }
        float bias = b1[n0 + li];
        #pragma unroll
        for (int r = 0; r < 4; ++r) {
            float hv = fmaxf(acc[r] + bias, 0.f);
            int m = quad * 4 + r;                 // C layout: row = quad*4+reg
            sH[m * SHS + n0 + li] = f2bf(hv);     // col = li
        }
    }
    __syncthreads();

    // A fragments for GEMM2 from LDS
    v8s aH[16];
    #pragma unroll
    for (int ks = 0; ks < 16; ++ks)
        aH[ks] = *(const v8s*)(sH + li * SHS + ks * 32 + quad * 8);

    // GEMM2: this wave covers output cols [wave*16, wave*16+16)
    {
        const int n0 = wave * 16;
        const unsigned short* wp = W2T + (size_t)(n0 + li) * D_H + quad * 8;
        v4f acc = {0.f, 0.f, 0.f, 0.f};
        #pragma unroll
        for (int kc = 0; kc < 2; ++kc) {
            v8s bb[8];
            #pragma unroll
            for (int u = 0; u < 8; ++u)
                bb[u] = *(const v8s*)(wp + (kc * 8 + u) * 32);
            #pragma unroll
            for (int u = 0; u < 8; ++u)
                acc = __builtin_amdgcn_mfma_f32_16x16x32_bf16(aH[kc * 8 + u], bb[u], acc, 0, 0, 0);
        }
        float bias = b2[n0 + li];
        #pragma unroll
        for (int r = 0; r < 4; ++r) {
            int grow = row0 + quad * 4 + r;
            if (grow < N)
                hh[(size_t)grow * D_F + n0 + li] = (_Float16)(acc[r] + bias);
        }
    }
}

// ---------------------------------------------------------------------------
// Edge stage: one wave per 2 exact 64-edge tiles (chunk is 64-aligned -> no
// wasted clamped gathers). Lane l owns dims {2l,2l+1}; each gather covers ONE
// row (fully coalesced 256 B). __shfl broadcast, 16-edge batches (32 loads
// in flight). Per-lane accumulation; reduce only at segment flush.
// ---------------------------------------------------------------------------
__global__ __launch_bounds__(256) void edge_kernel(
    const _Float16* __restrict__ hh, const float* __restrict__ wedge,
    const int* __restrict__ senders, const int* __restrict__ receivers,
    const int* __restrict__ ec,
    float* __restrict__ ew, float* __restrict__ ga,
    int E, int G, int chunk)
{
    __shared__ int   sec[513];
    __shared__ float sga[512];
    __shared__ float sew[512];
    const int t = threadIdx.x;
    for (int i = t; i <= G; i += 256) sec[i] = ec[i];
    for (int i = t; i < G;  i += 256) { sga[i] = 0.f; sew[i] = 0.f; }
    __syncthreads();

    const unsigned* __restrict__ h32 = (const unsigned*)hh;   // row = 64 dwords
    const int lane = t & 63;
    const int wid  = blockIdx.x * 4 + (t >> 6);
    const int e0 = wid * chunk;
    const int e1 = min(E, e0 + chunk);

    if (e0 < e1) {
        int gid;
        { int lo = 0, hi = G - 1;
          while (lo < hi) { int m = (lo + hi + 1) >> 1; if (sec[m] <= e0) lo = m; else hi = m - 1; }
          gid = lo; }

        float accE = 0.f, accW = 0.f;

        for (int tb = e0; tb < e1; tb += 64) {
            const int nt  = min(64, e1 - tb);
            const int ecl = min(tb + lane, e1 - 1);
            const bool vld = (tb + lane) < e1;
            int   sv = __builtin_nontemporal_load(senders + ecl);
            int   rv = __builtin_nontemporal_load(receivers + ecl);
            float wv = vld ? __builtin_nontemporal_load(wedge + ecl) : 0.f;

            if (nt == 64 && tb + 64 <= sec[gid + 1]) {
                // fast path: full tile in current segment
                #pragma unroll 1
                for (int i = 0; i < 64; i += 16) {
                    unsigned a[16], b[16];
                    int su[16], ru[16];
                    #pragma unroll
                    for (int u = 0; u < 16; ++u) {
                        su[u] = __shfl(sv, i + u);
                        ru[u] = __shfl(rv, i + u);
                    }
                    #pragma unroll
                    for (int u = 0; u < 16; ++u) {
                        a[u] = h32[(unsigned)((su[u] << 6) | lane)];
                        b[u] = h32[(unsigned)((ru[u] << 6) | lane)];
                    }
                    #pragma unroll
                    for (int u = 0; u < 16; ++u) {
                        float w = __shfl(wv, i + u);
                        v2h d  = bch(a[u]) - bch(b[u]);
                        float tt = __builtin_amdgcn_fdot2(d, d, 0.f, false);
                        accE = fmaf(w, tt, accE);
                    }
                }
                accW += wv;   // own-lane weight; lane-sum = tile sum
            } else {
                // boundary/tail tile: per-edge with segment flushes
                for (int i = 0; i < nt; ++i) {
                    int e = tb + i;
                    while (e >= sec[gid + 1]) {
                        float rE = accE, rW = accW;
                        #pragma unroll
                        for (int m = 32; m > 0; m >>= 1) {
                            rE += __shfl_xor(rE, m);
                            rW += __shfl_xor(rW, m);
                        }
                        if (lane == 0 && (rE != 0.f || rW != 0.f)) {
                            atomicAdd(&sga[gid], rE);
                            atomicAdd(&sew[gid], rW);
                        }
                        accE = 0.f; accW = 0.f;
                        ++gid;
                    }
                    int   s = __shfl(sv, i);
                    int   r = __shfl(rv, i);
                    float w = __shfl(wv, i);
                    unsigned a = h32[(unsigned)((s << 6) | lane)];
                    unsigned b = h32[(unsigned)((r << 6) | lane)];
                    v2h d = bch(a) - bch(b);
                    float tt = __builtin_amdgcn_fdot2(d, d, 0.f, false);
                    accE = fmaf(w, tt, accE);
                    if (lane == 0) accW += w;
                }
            }
        }
        // final flush
        float rE = accE, rW = accW;
        #pragma unroll
        for (int m = 32; m > 0; m >>= 1) {
            rE += __shfl_xor(rE, m);
            rW += __shfl_xor(rW, m);
        }
        if (lane == 0 && (rE != 0.f || rW != 0.f)) {
            atomicAdd(&sga[gid], rE);
            atomicAdd(&sew[gid], rW);
        }
    }

    __syncthreads();
    for (int g = t; g < G; g += 256) {
        float vg = sga[g], vw = sew[g];
        if (vg != 0.f || vw != 0.f) {
            atomicAdd(&ga[g], vg);
            atomicAdd(&ew[g], vw);
        }
    }
}

// ---------------------------------------------------------------------------
// Finalize: block g < G gathers node_out row; block G computes loss.
// ---------------------------------------------------------------------------
__global__ __launch_bounds__(128) void finalize_kernel(
    const _Float16* __restrict__ hh, const int* __restrict__ nid,
    const float* __restrict__ ew, const float* __restrict__ ga,
    float* __restrict__ out, int G)
{
    const int g = blockIdx.x;
    const int t = threadIdx.x;
    if (g < G) {
        int src = nid[g];
        out[(size_t)g * D_F + t] = (float)hh[(size_t)src * D_F + t];
    } else {
        float p = 0.f;
        for (int i = t; i < G; i += 128) {
            float w = ew[i];
            p += (w != 0.f) ? ga[i] / w : 0.f;
        }
        #pragma unroll
        for (int m = 32; m > 0; m >>= 1) p += __shfl_xor(p, m);
        __shared__ float sp[2];
        if ((t & 63) == 0) sp[t >> 6] = p;
        __syncthreads();
        if (t == 0) out[(size_t)G * D_F] = (sp[0] + sp[1]) / (float)G;
    }
}

// ---------------------------------------------------------------------------
extern "C" void kernel_launch(void* const* d_in, const int* in_sizes, int n_in,
                              void* d_out, int out_size, void* d_ws, size_t ws_size,
                              hipStream_t stream) {
    const float* nodes     = (const float*)d_in[0];
    const float* edges     = (const float*)d_in[1];
    const int*   senders   = (const int*)d_in[2];
    const int*   receivers = (const int*)d_in[3];
    const int*   n_node    = (const int*)d_in[4];
    const int*   n_edge    = (const int*)d_in[5];
    const float* W1        = (const float*)d_in[6];
    const float* b1        = (const float*)d_in[7];
    const float* W2        = (const float*)d_in[8];
    const float* b2        = (const float*)d_in[9];

    const int N = in_sizes[0] / D_F;
    const int E = in_sizes[1];
    const int G = in_sizes[4];

    float* out = (float*)d_out;

    // workspace: hh f16 | W1T bf16 | W2T bf16 | ec | nid | ew | ga
    _Float16*       hh  = (_Float16*)d_ws;
    unsigned short* W1T = (unsigned short*)(hh + (size_t)N * D_F);
    unsigned short* W2T = W1T + (size_t)D_F * D_H;
    int*            ec  = (int*)(W2T + (size_t)D_F * D_H);
    int*            nid = ec + (G + 1);
    float*          ew  = (float*)(nid + G);
    float*          ga  = ew + G;

    prep_kernel<<<(D_F * D_H + 255) / 256, 256, 0, stream>>>(
        W1, W2, n_node, n_edge, W1T, W2T, ec, nid, ew, ga, G, E);

    const int nblk = (N + 15) / 16;
    mlp_mfma_kernel<<<nblk, 512, 0, stream>>>(nodes, W1T, b1, W2T, b2, hh, N);

    // chunk: 64-aligned so every full tile avoids clamped-gather waste.
    const int nwaves = 5000;
    int chunk = (E + nwaves - 1) / nwaves;
    chunk = (chunk + 63) & ~63;
    const int nblkE = (((E + chunk - 1) / chunk) + 3) / 4;
    edge_kernel<<<nblkE, 256, 0, stream>>>(hh, edges, senders, receivers, ec,
                                           ew, ga, E, G, chunk);

    finalize_kernel<<<G + 1, 128, 0, stream>>>(hh, nid, ew, ga, out, G);
}